// Round 5
// baseline (149.749 us; speedup 1.0000x reference)
//
#include <hip/hip_runtime.h>
#include <math.h>

#define HH 256
#define WW 256
#define BB 8
#define MM 256
#define NN (HH * WW)
#define TPB 256
#define ROWS_PER_BLK 2
#define PIX_PER_BLK (WW * ROWS_PER_BLK)   // 512
#define BLKS_PER_B (NN / PIX_PER_BLK)     // 128
#define NBLK (BB * BLKS_PER_B)            // 1024 blocks = 4/CU = 4 waves/SIMD

#define EPSI 1e-6f
#define MAXD 362.03867196751236f
#define EPS_OVER_MAXD (1e-6f / 362.03867196751236f)

static __device__ __forceinline__ float asqrt(float x) {
    return __builtin_amdgcn_sqrtf(x);     // single v_sqrt_f32
}

// ws layout (uints): [0] counter | [16..16+2047] gmin (INVERTED float bits:
// memset-0 == +inf under unsigned atomicMax) | [2064..] per-block partials.
__global__ __launch_bounds__(256, 4) void whd_fused(
    const float* __restrict__ pm, const float* __restrict__ gt,
    const float* __restrict__ osz, float* __restrict__ out,
    unsigned* __restrict__ ws0)
{
    unsigned* ctr  = ws0;
    unsigned* gmin = ws0 + 16;                 // BB*MM
    unsigned* part = ws0 + 16 + BB * MM;       // NBLK*2

    __shared__ __align__(16) float2 sgt[MM];           // scaled GT points
    __shared__ __align__(16) float2 ssc[PIX_PER_BLK];  // (sc, EPSI*sc) per pixel
    __shared__ float swred[8];
    __shared__ float tsum[BB];
    __shared__ float gred[4];
    __shared__ int   lastFlag;

    const int tid = threadIdx.x;
    const int blk = blockIdx.x;   // 0..127
    const int b   = blockIdx.y;

    const float nfY = osz[b * 2 + 0] * (1.0f / HH);
    const float nfX = osz[b * 2 + 1] * (1.0f / WW);

    // stage scaled GT points
    {
        const float2 g = ((const float2*)gt)[b * MM + tid];
        sgt[tid] = make_float2(g.x * nfY, g.y * nfX);
    }

    // this thread's 2 pixels: one row, 2 consecutive cols
    const int   half = tid >> 7;                    // which of the 2 rows
    const int   c2   = (tid & 127) * 2;             // first col
    const int   row  = blk * ROWS_PER_BLK + half;
    const float y    = (float)row * nfY;
    const float x0   = (float)c2 * nfX;
    const float x1   = (float)(c2 + 1) * nfX;

    const float2 pv = *(const float2*)(pm + b * NN + row * WW + c2);
    const float p0 = pv.x, p1 = pv.y;
    const float q0 = p0 * p0, q1 = p1 * p1;
    const float sc0 = 1.0f / (q0 * q0 + EPS_OVER_MAXD);   // 1/(p^4 + EPS/MAXD)
    const float sc1 = 1.0f / (q1 * q1 + EPS_OVER_MAXD);

    // stage (sc, EPSI*sc) for phase B (16B store, conflict-free)
    *(float4*)&ssc[half * WW + c2] = make_float4(sc0, EPSI * sc0, sc1, EPSI * sc1);
    __syncthreads();

    // ---- Phase A: per-pixel min_m d^2 (broadcast m-loop; NO atomics/shuffles)
    float mind2a = INFINITY, mind2b = INFINITY;
    #pragma unroll 8
    for (int m = 0; m < MM; ++m) {
        const float2 g = sgt[m];          // uniform addr -> broadcast, free
        float ey = y - g.x;  ey *= ey;
        const float dx0 = x0 - g.y;
        const float dx1 = x1 - g.y;
        mind2a = fminf(mind2a, fmaf(dx0, dx0, ey));
        mind2b = fminf(mind2b, fmaf(dx1, dx1, ey));
    }

    // ---- Phase B: per-m min over this block's pixels (thread owns m = tid;
    // column min in a REGISTER, broadcast pixel reads, NO atomics in loop)
    const float2 gm = sgt[tid];
    float cmin = INFINITY;
    for (int h = 0; h < ROWS_PER_BLK; ++h) {
        const float yy  = (float)(blk * ROWS_PER_BLK + h) * nfY;
        const float dy  = yy - gm.x;
        const float dy2 = dy * dy;
        #pragma unroll 8
        for (int c = 0; c < WW; ++c) {
            const float2 s  = ssc[h * WW + c];    // uniform addr -> broadcast
            const float xx  = (float)c * nfX;     // uniform
            const float dx  = xx - gm.y;
            const float d2  = fmaf(dx, dx, dy2);
            const float v   = fmaf(asqrt(d2), s.x, s.y);   // (d+EPS)/(p^4+..)
            cmin = fminf(cmin, v);
        }
    }

    // ---- epilogue: term1 partial sums (thread-exclusive pixels)
    float sum0 = p0 + p1;
    float sum1 = fmaf(p0, asqrt(mind2a), p1 * asqrt(mind2b));
    #pragma unroll
    for (int off = 32; off; off >>= 1) {
        sum0 += __shfl_down(sum0, off, 64);
        sum1 += __shfl_down(sum1, off, 64);
    }
    if ((tid & 63) == 0) { swred[(tid >> 6) * 2] = sum0; swred[(tid >> 6) * 2 + 1] = sum1; }
    __syncthreads();

    const int blin = b * BLKS_PER_B + blk;
    if (tid == 0) {
        const float s0 = (swred[0] + swred[2]) + (swred[4] + swred[6]);
        const float s1 = (swred[1] + swred[3]) + (swred[5] + swred[7]);
        atomicExch(&part[blin * 2 + 0], __float_as_uint(s0));
        atomicExch(&part[blin * 2 + 1], __float_as_uint(s1));
    }
    // merge this block's per-m column min into global (inverted bits -> max)
    atomicMax(&gmin[b * MM + tid], ~__float_as_uint(cmin));

    // ---- last-block combine
    __threadfence();
    if (tid == 0) lastFlag = (atomicAdd(ctr, 1u) == NBLK - 1);
    __syncthreads();
    if (!lastFlag) return;
    __threadfence();

    // term2: mean of clipped per-(b,m) minima
    float gacc = 0.0f;
    #pragma unroll
    for (int q = 0; q < BB; ++q) {
        const float v = __uint_as_float(~atomicOr(&gmin[q * MM + tid], 0u));
        gacc += fminf(fmaxf(v, 0.0f), MAXD);
    }
    #pragma unroll
    for (int off = 32; off; off >>= 1) gacc += __shfl_down(gacc, off, 64);
    if ((tid & 63) == 0) gred[tid >> 6] = gacc;

    // term1: per-batch ratios from per-block partials (8 batches x 32 lanes)
    {
        const int bb = tid >> 5, r = tid & 31;
        float s0 = 0.0f, s1 = 0.0f;
        #pragma unroll
        for (int q = 0; q < BLKS_PER_B / 32; ++q) {   // 4
            const int bl = bb * BLKS_PER_B + r + q * 32;
            s0 += __uint_as_float(atomicOr(&part[bl * 2 + 0], 0u));
            s1 += __uint_as_float(atomicOr(&part[bl * 2 + 1], 0u));
        }
        #pragma unroll
        for (int off = 16; off; off >>= 1) {
            s0 += __shfl_down(s0, off, 32);
            s1 += __shfl_down(s1, off, 32);
        }
        if (r == 0) tsum[bb] = s1 / (s0 + EPSI);
    }
    __syncthreads();
    if (tid == 0) {
        float t1 = 0.0f;
        #pragma unroll
        for (int q = 0; q < BB; ++q) t1 += tsum[q];
        const float g2 = (gred[0] + gred[1]) + (gred[2] + gred[3]);
        out[0] = t1 * (1.0f / BB) + g2 * (1.0f / (BB * MM));
    }
}

extern "C" void kernel_launch(void* const* d_in, const int* in_sizes, int n_in,
                              void* d_out, int out_size, void* d_ws, size_t ws_size,
                              hipStream_t stream) {
    const float* pm  = (const float*)d_in[0];   // [B, H, W]
    const float* gt  = (const float*)d_in[1];   // [B, M, 2]
    const float* osz = (const float*)d_in[2];   // [B, 2]
    float* out = (float*)d_out;
    unsigned* ws0 = (unsigned*)d_ws;

    // counter + gmin zero-init (gmin inverted bits: 0 == +inf)
    hipMemsetAsync(ws0, 0, (16 + BB * MM) * sizeof(unsigned), stream);

    dim3 grid(BLKS_PER_B, BB);
    whd_fused<<<grid, 256, 0, stream>>>(pm, gt, osz, out, ws0);
}